// Round 9
// baseline (138.058 us; speedup 1.0000x reference)
//
#include <hip/hip_runtime.h>
#include <hip/hip_bf16.h>
#include <math.h>
#include <stdint.h>

// MultiHeadDenseAttention: B=2, H=16, N=2048, D=64, F=1024, M=2048
//  value = x @ Wv^T -> vt[bh][d][m]  (128x64 GEMM, 2 blocks/CU)
//  hid   = relu(xh @ W1^T + b1)      (fused into flash prologue, MFMA 32x32)
//  attn  = softmax(hid @ W2^T + b2)  (flash, swapped-QK^T, exp2, no-max,
//                                     bias as S C-init; L = scalar lane sum)
//  out_h = attn @ vh                 (fused, P in-register, 8-wave m-parallel)
//  out   = merge(out_h) @ Wo^T       (128x64 GEMM, fp32 out)

typedef __attribute__((ext_vector_type(8))) short bf16x8;
typedef __attribute__((ext_vector_type(4))) float f32x4;
typedef __attribute__((ext_vector_type(16))) float f32x16;

#define LOG2E 1.4426950408889634f

__device__ __forceinline__ unsigned short f2bf(float f) {
  union { float f; unsigned u; } v; v.f = f;
  unsigned r = v.u + 0x7FFFu + ((v.u >> 16) & 1u);   // round-to-nearest-even
  return (unsigned short)(r >> 16);
}

// ------------- one-shot prep: x/Wv/Wo/W2/W1 -> bf16, b2 -> b2*log2e ---------
__global__ __launch_bounds__(256) void prep_all(const float* __restrict__ x,
                                                const float* __restrict__ Wv,
                                                const float* __restrict__ Wo,
                                                const float* __restrict__ W2,
                                                const float* __restrict__ W1,
                                                const float* __restrict__ b2,
                                                unsigned short* __restrict__ xb,
                                                unsigned short* __restrict__ wvb,
                                                unsigned short* __restrict__ wob,
                                                unsigned short* __restrict__ w2b,
                                                unsigned short* __restrict__ w1b,
                                                float* __restrict__ b2l) {
  int bid = blockIdx.x;
  if (bid == 2048) {                                 // b2 * log2e table
    int i = threadIdx.x;
#pragma unroll
    for (int t = 0; t < 8; ++t) {
      int k = i * 8 + t;
      b2l[k] = b2[k] * LOG2E;
    }
    return;
  }
  int stride = 2048 * 256;
  for (int q = bid * 256 + threadIdx.x; q < 1606656; q += stride) {
    const float* s; unsigned short* d; int o;
    if (q < 1048576)      { s = x;  d = xb;  o = q; }
    else {
      int q2 = q - 1048576;
      if (q2 < 262144)      { s = Wv; d = wvb; o = q2; }
      else if (q2 < 524288) { s = Wo; d = wob; o = q2 - 262144; }
      else if (q2 < 557056) { s = W2; d = w2b; o = q2 - 524288; }
      else                  { s = W1; d = w1b; o = q2 - 557056; }
    }
    float4 v = *(const float4*)(s + (size_t)o * 4);
    uint2 u;
    u.x = (unsigned)f2bf(v.x) | ((unsigned)f2bf(v.y) << 16);
    u.y = (unsigned)f2bf(v.z) | ((unsigned)f2bf(v.w) << 16);
    *(uint2*)(d + (size_t)o * 4) = u;
  }
}

// ---------------- shared staging/frag helpers ----------------
// 4-wave version: wave w stages rows w*16..w*16+15 (2 insts)
__device__ __forceinline__ void stage64(const char* g, size_t ldbytes, char* lds,
                                        int w, int lane) {
#pragma unroll
  for (int t = 0; t < 2; ++t) {
    int row  = w * 16 + t * 8 + (lane >> 3);
    int csrc = (lane & 7) ^ (lane >> 3);
    const char* src = g + (size_t)row * ldbytes + (csrc << 4);
    char* dst = lds + ((w * 2 + t) << 10);
    __builtin_amdgcn_global_load_lds((const __attribute__((address_space(1))) void*)src,
                                     (__attribute__((address_space(3))) void*)dst,
                                     16, 0, 0);
  }
}

// 8-wave version: wave w stages rows w*8..w*8+7 (1 inst)
__device__ __forceinline__ void stage8(const char* g, size_t ldbytes, char* lds_,
                                       int w, int lane) {
  int row  = w * 8 + (lane >> 3);                 // row & 7 == lane>>3
  int csrc = (lane & 7) ^ (lane >> 3);
  const char* src = g + (size_t)row * ldbytes + (csrc << 4);
  char* dst = lds_ + (w << 10);
  __builtin_amdgcn_global_load_lds((const __attribute__((address_space(1))) void*)src,
                                   (__attribute__((address_space(3))) void*)dst,
                                   16, 0, 0);
}

// 32x32x16 operand fragment: row index linear (128B rows), chunk = kslice*2 + hi
__device__ __forceinline__ bf16x8 rdfrag32(const char* lds, int row, int chunk) {
  int c = chunk ^ (row & 7);
  return *(const bf16x8*)(lds + row * 128 + (c << 4));
}

// Load 16 fp32 in the 32x32 C/D reg layout: reg r <- p[(r&3) + 8*(r>>2)]
__device__ __forceinline__ f32x16 loadb16(const float* p) {
  f32x16 r;
#pragma unroll
  for (int qd = 0; qd < 4; ++qd) {
    float4 v = *(const float4*)(p + qd * 8);
    r[qd * 4 + 0] = v.x; r[qd * 4 + 1] = v.y; r[qd * 4 + 2] = v.z; r[qd * 4 + 3] = v.w;
  }
  return r;
}

// Build a 32x32x16 A/B-frag (8 bf16) from 16 C/D-layout f32 regs via cvt_pk+permlane.
__device__ __forceinline__ bf16x8 pk_swap(float r0, float r1, float r2, float r3,
                                          float r4, float r5, float r6, float r7) {
  unsigned a, b, c, d;
  asm("v_cvt_pk_bf16_f32 %0, %1, %2" : "=v"(a) : "v"(r0), "v"(r1));
  asm("v_cvt_pk_bf16_f32 %0, %1, %2" : "=v"(b) : "v"(r4), "v"(r5));
  asm("v_cvt_pk_bf16_f32 %0, %1, %2" : "=v"(c) : "v"(r2), "v"(r3));
  asm("v_cvt_pk_bf16_f32 %0, %1, %2" : "=v"(d) : "v"(r6), "v"(r7));
  asm("v_permlane32_swap_b32 %0, %1" : "+v"(a), "+v"(b));
  asm("v_permlane32_swap_b32 %0, %1" : "+v"(c), "+v"(d));
  union { unsigned u[4]; bf16x8 v; } r;
  r.u[0] = a; r.u[1] = c; r.u[2] = b; r.u[3] = d;
  return r.v;
}

// ---------------- GEMM: C = A @ B^T, 128x64 tile, 32x32 MFMA ----------------
// grid (32,16) = 512 blocks -> 2 blocks/CU. 4 waves 2x2; wave = 64 rows x 32 cols.
// MODE 0: vt[bh*64+d][2048] bf16 (value projection, per-head transpose)
// MODE 1: fp32 row-major [M][1024]
template<int MODE>
__global__ __launch_bounds__(256) void gemm12864(const unsigned short* __restrict__ A,
                                                 const unsigned short* __restrict__ B,
                                                 void* __restrict__ C, int K) {
  __shared__ __attribute__((aligned(16))) char As[2][16384];   // 128 rows
  __shared__ __attribute__((aligned(16))) char Bs[2][8192];    // 64 rows
  int tid = threadIdx.x, w = tid >> 6, lane = tid & 63;
  int l31 = lane & 31, hi = lane >> 5;
  int wr = w >> 1, wc = w & 1;
  int bm = blockIdx.x, bn = blockIdx.y;
  const char* Ab = (const char*)A + (size_t)bm * 128 * (K * 2);
  const char* Bb = (const char*)B + (size_t)bn * 64 * (K * 2);
  size_t ld = (size_t)K * 2;

  f32x16 acc0 = {}, acc1 = {};
  stage64(Ab, ld, As[0], w, lane);
  stage64(Ab + 64 * ld, ld, As[0] + 8192, w, lane);
  stage64(Bb, ld, Bs[0], w, lane);
  __syncthreads();

  int nst = K >> 6;
  for (int kk = 0; kk < nst; ++kk) {
    int cur = kk & 1;
    if (kk + 1 < nst) {
      const char* An = Ab + (size_t)(kk + 1) * 128;
      const char* Bn = Bb + (size_t)(kk + 1) * 128;
      stage64(An, ld, As[cur ^ 1], w, lane);
      stage64(An + 64 * ld, ld, As[cur ^ 1] + 8192, w, lane);
      stage64(Bn, ld, Bs[cur ^ 1], w, lane);
    }
    __builtin_amdgcn_s_setprio(1);
#pragma unroll
    for (int ks = 0; ks < 4; ++ks) {
      bf16x8 a0 = rdfrag32(As[cur], wr * 64 + l31, ks * 2 + hi);
      bf16x8 a1 = rdfrag32(As[cur], wr * 64 + 32 + l31, ks * 2 + hi);
      bf16x8 b0 = rdfrag32(Bs[cur], wc * 32 + l31, ks * 2 + hi);
      acc0 = __builtin_amdgcn_mfma_f32_32x32x16_bf16(a0, b0, acc0, 0, 0, 0);
      acc1 = __builtin_amdgcn_mfma_f32_32x32x16_bf16(a1, b0, acc1, 0, 0, 0);
    }
    __builtin_amdgcn_s_setprio(0);
    __syncthreads();
  }

  if (MODE == 0) {
    unsigned short* vt = (unsigned short*)C;
    int d = wc * 32 + l31;
#pragma unroll
    for (int i = 0; i < 2; ++i) {
      f32x16 a = i ? acc1 : acc0;
      int rowb = bm * 128 + wr * 64 + i * 32;
#pragma unroll
      for (int qd = 0; qd < 4; ++qd) {
        int m0 = rowb + qd * 8 + hi * 4;          // 4 consecutive m (r=qd*4+0..3)
        int bb = m0 >> 11, n = m0 & 2047;
        int r0 = qd * 4;
        uint2 u;
        u.x = (unsigned)f2bf(a[r0]) | ((unsigned)f2bf(a[r0 + 1]) << 16);
        u.y = (unsigned)f2bf(a[r0 + 2]) | ((unsigned)f2bf(a[r0 + 3]) << 16);
        *(uint2*)(vt + ((size_t)((bb * 16 + bn) * 64 + d)) * 2048 + n) = u;
      }
    }
  } else {
    float* Cf = (float*)C;
    int rb = bm * 128 + wr * 64, cb = bn * 64 + wc * 32;
#pragma unroll
    for (int r = 0; r < 16; ++r) {
      int row = (r & 3) + 8 * (r >> 2) + 4 * hi;
      Cf[(size_t)(rb + row) * 1024 + cb + l31]      = acc0[r];
      Cf[(size_t)(rb + 32 + row) * 1024 + cb + l31] = acc1[r];
    }
  }
}

// ---------------- fused dense attention (8-wave, m-parallel groups) ----------
// Block: 128 q rows, 8 waves. Group grp=w>>2: grp0 even m-tiles, grp1 odd.
// 4-slot LDS ring; stage 2 tiles ahead; one barrier per superstep (2 tiles).
// Bias as S C-init (log2 domain, prefetched); L = per-lane scalar sum (swapped
// QK^T makes the q-row lane-local). End: O/L combined across groups via LDS.
__global__ __launch_bounds__(512, 4) void flash_kernel(const unsigned short* __restrict__ xb,
                                                       const unsigned short* __restrict__ w1b,
                                                       const float* __restrict__ b1,
                                                       const unsigned short* __restrict__ w2b,
                                                       const float* __restrict__ b2l,
                                                       const unsigned short* __restrict__ vt,
                                                       unsigned short* __restrict__ aout) {
  __shared__ __attribute__((aligned(16))) char lds[65536];
  int tid = threadIdx.x, w = tid >> 6, lane = tid & 63;
  int wq = w & 3, grp = w >> 2;
  int l31 = lane & 31, hi = lane >> 5;
  // XCD-chunked swizzle: 512 blocks, 8 XCDs
  int f = blockIdx.x;
  int swz = ((f & 7) << 6) | (f >> 3);
  int qt = swz & 15, bh = swz >> 4;
  int b = bh >> 4, h = bh & 15;

  // ---- prologue: Q = relu(xh @ W1^T + b1) * log2e, in-register ----
  const char* px = (const char*)(xb + ((size_t)(b * 2048 + qt * 128)) * 1024 + h * 64);
  stage8(px, 2048, lds, w, lane);                          // x rows 0..63
  stage8(px + (size_t)64 * 2048, 2048, lds + 8192, w, lane); // x rows 64..127
  stage8((const char*)w1b, 128, lds + 32768, w, lane);     // W1 rows e 0..63
  __syncthreads();

  f32x16 h0 = loadb16(b1 + hi * 4);
  f32x16 h1 = loadb16(b1 + 32 + hi * 4);
  {
    const char* xt = lds + (wq >> 1) * 8192;
    int xr = (wq & 1) * 32 + l31;
#pragma unroll
    for (int ks = 0; ks < 4; ++ks) {
      bf16x8 xf = rdfrag32(xt, xr, ks * 2 + hi);           // B: x^T (col=q)
      bf16x8 wf0 = rdfrag32(lds + 32768, l31, ks * 2 + hi);
      h0 = __builtin_amdgcn_mfma_f32_32x32x16_bf16(wf0, xf, h0, 0, 0, 0);
      bf16x8 wf1 = rdfrag32(lds + 32768, 32 + l31, ks * 2 + hi);
      h1 = __builtin_amdgcn_mfma_f32_32x32x16_bf16(wf1, xf, h1, 0, 0, 0);
    }
  }
#pragma unroll
  for (int i = 0; i < 16; ++i) {
    h0[i] = fmaxf(h0[i], 0.f) * LOG2E;
    h1[i] = fmaxf(h1[i], 0.f) * LOG2E;
  }
  bf16x8 qb[4];
  qb[0] = pk_swap(h0[0], h0[1], h0[2], h0[3], h0[4], h0[5], h0[6], h0[7]);
  qb[1] = pk_swap(h0[8], h0[9], h0[10], h0[11], h0[12], h0[13], h0[14], h0[15]);
  qb[2] = pk_swap(h1[0], h1[1], h1[2], h1[3], h1[4], h1[5], h1[6], h1[7]);
  qb[3] = pk_swap(h1[8], h1[9], h1[10], h1[11], h1[12], h1[13], h1[14], h1[15]);
  __syncthreads();                                  // all waves done with prologue LDS

  // ---- stage tiles 0..3 into the 4-slot ring; prefetch first bias ----
  const char* vtb = (const char*)vt + (size_t)bh * 64 * 4096;
#pragma unroll
  for (int t = 0; t < 4; ++t) {
    stage8((const char*)w2b + (size_t)t * 8192, 128, lds + t * 8192, w, lane);
    stage8(vtb + (size_t)t * 128, 4096, lds + 32768 + t * 8192, w, lane);
  }
  f32x4 pre0[4], pre1[4];                           // bias C-init (log2 domain)
#pragma unroll
  for (int qd = 0; qd < 4; ++qd) {
    pre0[qd] = *(const f32x4*)(b2l + grp * 64 + qd * 8 + hi * 4);
    pre1[qd] = *(const f32x4*)(b2l + grp * 64 + 32 + qd * 8 + hi * 4);
  }
  f32x16 oA = {}, oB = {};
  float lrs0 = 0.f, lrs1 = 0.f, lrs2 = 0.f, lrs3 = 0.f;
  __syncthreads();                                  // tiles 0..3 landed

  for (int s = 0; s < 16; ++s) {
    int mt = 2 * s + grp;
    const char* Kc = lds + (mt & 3) * 8192;
    const char* Vc = lds + 32768 + (mt & 3) * 8192;

    // S^T = K @ Q + bias (log2 domain), C-init from prefetched bias
    f32x16 s0, s1;
#pragma unroll
    for (int qd = 0; qd < 4; ++qd) {
#pragma unroll
      for (int j = 0; j < 4; ++j) {
        s0[qd * 4 + j] = pre0[qd][j];
        s1[qd * 4 + j] = pre1[qd][j];
      }
    }
    __builtin_amdgcn_s_setprio(1);
#pragma unroll
    for (int kt = 0; kt < 4; ++kt) {
      bf16x8 kf0 = rdfrag32(Kc, l31, kt * 2 + hi);
      s0 = __builtin_amdgcn_mfma_f32_32x32x16_bf16(kf0, qb[kt], s0, 0, 0, 0);
      bf16x8 kf1 = rdfrag32(Kc, 32 + l31, kt * 2 + hi);
      s1 = __builtin_amdgcn_mfma_f32_32x32x16_bf16(kf1, qb[kt], s1, 0, 0, 0);
    }
    __builtin_amdgcn_s_setprio(0);
    if (s < 15) {                                   // prefetch next bias (mt+2)
#pragma unroll
      for (int qd = 0; qd < 4; ++qd) {
        pre0[qd] = *(const f32x4*)(b2l + (mt + 2) * 64 + qd * 8 + hi * 4);
        pre1[qd] = *(const f32x4*)(b2l + (mt + 2) * 64 + 32 + qd * 8 + hi * 4);
      }
    }
    // p = 2^s ; per-lane scalar row-sum (4-way split)
#pragma unroll
    for (int i = 0; i < 16; ++i) {
      float t0, t1;
      asm("v_exp_f32 %0, %1" : "=v"(t0) : "v"(s0[i]));
      asm("v_exp_f32 %0, %1" : "=v"(t1) : "v"(s1[i]));
      s0[i] = t0; s1[i] = t1;
      if ((i & 3) == 0) { lrs0 += t0; lrs0 += t1; }
      else if ((i & 3) == 1) { lrs1 += t0; lrs1 += t1; }
      else if ((i & 3) == 2) { lrs2 += t0; lrs2 += t1; }
      else { lrs3 += t0; lrs3 += t1; }
    }
    bf16x8 pa0 = pk_swap(s0[0], s0[1], s0[2], s0[3], s0[4], s0[5], s0[6], s0[7]);
    bf16x8 pa1 = pk_swap(s0[8], s0[9], s0[10], s0[11], s0[12], s0[13], s0[14], s0[15]);
    bf16x8 pa2 = pk_swap(s1[0], s1[1], s1[2], s1[3], s1[4], s1[5], s1[6], s1[7]);
    bf16x8 pa3 = pk_swap(s1[8], s1[9], s1[10], s1[11], s1[12], s1[13], s1[14], s1[15]);
    // O += P @ V
    __builtin_amdgcn_s_setprio(1);
    {
      bf16x8 vf;
      vf = rdfrag32(Vc, l31, 0 + hi);
      oA = __builtin_amdgcn_mfma_f32_32x32x16_bf16(pa0, vf, oA, 0, 0, 0);
      vf = rdfrag32(Vc, 32 + l31, 0 + hi);
      oB = __builtin_amdgcn_mfma_f32_32x32x16_bf16(pa0, vf, oB, 0, 0, 0);
      vf = rdfrag32(Vc, l31, 2 + hi);
      oA = __builtin_amdgcn_mfma_f32_32x32x16_bf16(pa1, vf, oA, 0, 0, 0);
      vf = rdfrag32(Vc, 32 + l31, 2 + hi);
      oB = __builtin_amdgcn_mfma_f32_32x32x16_bf16(pa1, vf, oB, 0, 0, 0);
      vf = rdfrag32(Vc, l31, 4 + hi);
      oA = __builtin_amdgcn_mfma_f32_32x32x16_bf16(pa2, vf, oA, 0, 0, 0);
      vf = rdfrag32(Vc, 32 + l31, 4 + hi);
      oB = __builtin_amdgcn_mfma_f32_32x32x16_bf16(pa2, vf, oB, 0, 0, 0);
      vf = rdfrag32(Vc, l31, 6 + hi);
      oA = __builtin_amdgcn_mfma_f32_32x32x16_bf16(pa3, vf, oA, 0, 0, 0);
      vf = rdfrag32(Vc, 32 + l31, 6 + hi);
      oB = __builtin_amdgcn_mfma_f32_32x32x16_bf16(pa3, vf, oB, 0, 0, 0);
    }
    __builtin_amdgcn_s_setprio(0);
    __syncthreads();                       // both tiles of this superstep consumed
    if (s < 14) {                          // stage tiles 2s+4, 2s+5 (slots just freed)
      int t0 = 2 * s + 4, t1 = 2 * s + 5;
      stage8((const char*)w2b + (size_t)t0 * 8192, 128, lds + (t0 & 3) * 8192, w, lane);
      stage8(vtb + (size_t)t0 * 128, 4096, lds + 32768 + (t0 & 3) * 8192, w, lane);
      stage8((const char*)w2b + (size_t)t1 * 8192, 128, lds + (t1 & 3) * 8192, w, lane);
      stage8(vtb + (size_t)t1 * 128, 4096, lds + 32768 + (t1 & 3) * 8192, w, lane);
    }
  }

  // ---- combine groups (exact fp32 add), then finalize ----
  float lpart = (lrs0 + lrs1) + (lrs2 + lrs3);     // partial: this grp, own m-half
  float* comb = (float*)lds;
  if (grp == 1) {
    float* cb = comb + (wq * 64 + lane) * 36;      // 36-float stride, 16B aligned
#pragma unroll
    for (int i = 0; i < 4; ++i) {
      *(float4*)(cb + i * 4)      = make_float4(oA[i*4], oA[i*4+1], oA[i*4+2], oA[i*4+3]);
      *(float4*)(cb + 16 + i * 4) = make_float4(oB[i*4], oB[i*4+1], oB[i*4+2], oB[i*4+3]);
    }
    cb[32] = lpart;
  }
  __syncthreads();
  if (grp == 0) {
    float* cb = comb + (wq * 64 + lane) * 36;
#pragma unroll
    for (int i = 0; i < 4; ++i) {
      float4 a = *(const float4*)(cb + i * 4);
      float4 bq = *(const float4*)(cb + 16 + i * 4);
      oA[i*4] += a.x; oA[i*4+1] += a.y; oA[i*4+2] += a.z; oA[i*4+3] += a.w;
      oB[i*4] += bq.x; oB[i*4+1] += bq.y; oB[i*4+2] += bq.z; oB[i*4+3] += bq.w;
    }
    float l = lpart + cb[32];
    l += __shfl_xor(l, 32);                        // combine m-halves -> full L[q=l31]
    float inv = 1.f / l;
    float iv[16];
#pragma unroll
    for (int r = 0; r < 16; ++r)
      iv[r] = __shfl(inv, (r & 3) + 8 * (r >> 2) + 4 * hi);
    int nb = qt * 128 + wq * 32;
#pragma unroll
    for (int r = 0; r < 16; ++r) {
      int ql = (r & 3) + 8 * (r >> 2) + 4 * hi;
      size_t off = ((size_t)(b * 2048 + nb + ql)) * 1024 + h * 64 + l31;
      aout[off]      = f2bf(oA[r] * iv[r]);
      aout[off + 32] = f2bf(oB[r] * iv[r]);
    }
  }
}

// ---------------- launch ----------------
extern "C" void kernel_launch(void* const* d_in, const int* in_sizes, int n_in,
                              void* d_out, int out_size, void* d_ws, size_t ws_size,
                              hipStream_t stream) {
  (void)in_sizes; (void)n_in; (void)out_size; (void)ws_size;
  const float* x  = (const float*)d_in[0];
  const float* W1 = (const float*)d_in[1];
  const float* b1 = (const float*)d_in[2];
  const float* W2 = (const float*)d_in[3];
  const float* b2 = (const float*)d_in[4];
  const float* Wv = (const float*)d_in[5];
  const float* Wo = (const float*)d_in[6];
  float* out = (float*)d_out;

  char* ws = (char*)d_ws;
  unsigned short* xb   = (unsigned short*)(ws);             // x bf16      8 MB
  unsigned short* wvb  = (unsigned short*)(ws +  8388608);  // Wv bf16     2 MB
  unsigned short* wob  = (unsigned short*)(ws + 10485760);  // Wo bf16     2 MB
  unsigned short* w2b  = (unsigned short*)(ws + 12582912);  // W2 bf16   256 KB
  unsigned short* w1b  = (unsigned short*)(ws + 12845056);  // W1 bf16     8 KB
  float*          b2l  = (float*)         (ws + 12853248);  // b2*log2e    8 KB
  unsigned short* vt   = (unsigned short*)(ws + 21233664);  // V^T bf16    8 MB
  unsigned short* aout = (unsigned short*)(ws + 29622272);  // out_h bf16  8 MB

  prep_all<<<2049, 256, 0, stream>>>(x, Wv, Wo, W2, W1, b2,
                                     xb, wvb, wob, w2b, w1b, b2l);

  // value = x @ Wv^T -> vt[bh][d][m]
  gemm12864<0><<<dim3(32, 16), 256, 0, stream>>>(xb, wvb, (void*)vt, 1024);
  // fused: Q = relu(xh@W1^T+b1); softmax(Q@W2^T + b2) @ V -> aout (merged heads)
  flash_kernel<<<512, 512, 0, stream>>>(xb, w1b, b1, w2b, b2l, vt, aout);
  // out = aout @ Wo^T (fp32)
  gemm12864<1><<<dim3(32, 16), 256, 0, stream>>>(aout, wob, (void*)out, 1024);
}

// Round 10
// 94.217 us; speedup vs baseline: 1.4653x; 1.4653x over previous
//
#include <hip/hip_runtime.h>
#include <hip/hip_bf16.h>
#include <math.h>
#include <stdint.h>

// MultiHeadDenseAttention: B=2, H=16, N=2048, D=64, F=1024, M=2048
//  value = x @ Wv^T -> vt[bh][d][m]  (128x64 GEMM, 2 blocks/CU)
//  hid   = relu(xh @ W1^T + b1)      (fused into flash prologue, MFMA 32x32)
//  attn  = softmax(hid @ W2^T + b2)  (flash, swapped-QK^T, exp2, no-max,
//                                     bias as S C-init; L = scalar lane sum)
//  out_h = attn @ vh                 (fused, P in-register, 8-wave m-parallel)
//  out   = merge(out_h) @ Wo^T       (128x64 GEMM, fp32 out)

typedef __attribute__((ext_vector_type(8))) short bf16x8;
typedef __attribute__((ext_vector_type(4))) float f32x4;
typedef __attribute__((ext_vector_type(16))) float f32x16;

#define LOG2E 1.4426950408889634f

__device__ __forceinline__ unsigned short f2bf(float f) {
  union { float f; unsigned u; } v; v.f = f;
  unsigned r = v.u + 0x7FFFu + ((v.u >> 16) & 1u);   // round-to-nearest-even
  return (unsigned short)(r >> 16);
}

// ------------- one-shot prep: x/Wv/Wo/W2/W1 -> bf16, b2 -> b2*log2e ---------
__global__ __launch_bounds__(256) void prep_all(const float* __restrict__ x,
                                                const float* __restrict__ Wv,
                                                const float* __restrict__ Wo,
                                                const float* __restrict__ W2,
                                                const float* __restrict__ W1,
                                                const float* __restrict__ b2,
                                                unsigned short* __restrict__ xb,
                                                unsigned short* __restrict__ wvb,
                                                unsigned short* __restrict__ wob,
                                                unsigned short* __restrict__ w2b,
                                                unsigned short* __restrict__ w1b,
                                                float* __restrict__ b2l) {
  int bid = blockIdx.x;
  if (bid == 2048) {                                 // b2 * log2e table
    int i = threadIdx.x;
#pragma unroll
    for (int t = 0; t < 8; ++t) {
      int k = i * 8 + t;
      b2l[k] = b2[k] * LOG2E;
    }
    return;
  }
  int stride = 2048 * 256;
  for (int q = bid * 256 + threadIdx.x; q < 1606656; q += stride) {
    const float* s; unsigned short* d; int o;
    if (q < 1048576)      { s = x;  d = xb;  o = q; }
    else {
      int q2 = q - 1048576;
      if (q2 < 262144)      { s = Wv; d = wvb; o = q2; }
      else if (q2 < 524288) { s = Wo; d = wob; o = q2 - 262144; }
      else if (q2 < 557056) { s = W2; d = w2b; o = q2 - 524288; }
      else                  { s = W1; d = w1b; o = q2 - 557056; }
    }
    float4 v = *(const float4*)(s + (size_t)o * 4);
    uint2 u;
    u.x = (unsigned)f2bf(v.x) | ((unsigned)f2bf(v.y) << 16);
    u.y = (unsigned)f2bf(v.z) | ((unsigned)f2bf(v.w) << 16);
    *(uint2*)(d + (size_t)o * 4) = u;
  }
}

// ---------------- shared staging/frag helpers ----------------
// 4-wave version: wave w stages rows w*16..w*16+15 (2 insts)
__device__ __forceinline__ void stage64(const char* g, size_t ldbytes, char* lds,
                                        int w, int lane) {
#pragma unroll
  for (int t = 0; t < 2; ++t) {
    int row  = w * 16 + t * 8 + (lane >> 3);
    int csrc = (lane & 7) ^ (lane >> 3);
    const char* src = g + (size_t)row * ldbytes + (csrc << 4);
    char* dst = lds + ((w * 2 + t) << 10);
    __builtin_amdgcn_global_load_lds((const __attribute__((address_space(1))) void*)src,
                                     (__attribute__((address_space(3))) void*)dst,
                                     16, 0, 0);
  }
}

// 8-wave version: wave w stages rows w*8..w*8+7 (1 inst)
__device__ __forceinline__ void stage8(const char* g, size_t ldbytes, char* lds_,
                                       int w, int lane) {
  int row  = w * 8 + (lane >> 3);                 // row & 7 == lane>>3
  int csrc = (lane & 7) ^ (lane >> 3);
  const char* src = g + (size_t)row * ldbytes + (csrc << 4);
  char* dst = lds_ + (w << 10);
  __builtin_amdgcn_global_load_lds((const __attribute__((address_space(1))) void*)src,
                                   (__attribute__((address_space(3))) void*)dst,
                                   16, 0, 0);
}

// 32x32x16 operand fragment: row index linear (128B rows), chunk = kslice*2 + hi
__device__ __forceinline__ bf16x8 rdfrag32(const char* lds, int row, int chunk) {
  int c = chunk ^ (row & 7);
  return *(const bf16x8*)(lds + row * 128 + (c << 4));
}

// Load 16 fp32 in the 32x32 C/D reg layout: reg r <- p[(r&3) + 8*(r>>2)]
__device__ __forceinline__ f32x16 loadb16(const float* p) {
  f32x16 r;
#pragma unroll
  for (int qd = 0; qd < 4; ++qd) {
    float4 v = *(const float4*)(p + qd * 8);
    r[qd * 4 + 0] = v.x; r[qd * 4 + 1] = v.y; r[qd * 4 + 2] = v.z; r[qd * 4 + 3] = v.w;
  }
  return r;
}

// Build a 32x32x16 A/B-frag (8 bf16) from 16 C/D-layout f32 regs via cvt_pk+permlane.
__device__ __forceinline__ bf16x8 pk_swap(float r0, float r1, float r2, float r3,
                                          float r4, float r5, float r6, float r7) {
  unsigned a, b, c, d;
  asm("v_cvt_pk_bf16_f32 %0, %1, %2" : "=v"(a) : "v"(r0), "v"(r1));
  asm("v_cvt_pk_bf16_f32 %0, %1, %2" : "=v"(b) : "v"(r4), "v"(r5));
  asm("v_cvt_pk_bf16_f32 %0, %1, %2" : "=v"(c) : "v"(r2), "v"(r3));
  asm("v_cvt_pk_bf16_f32 %0, %1, %2" : "=v"(d) : "v"(r6), "v"(r7));
  asm("v_permlane32_swap_b32 %0, %1" : "+v"(a), "+v"(b));
  asm("v_permlane32_swap_b32 %0, %1" : "+v"(c), "+v"(d));
  union { unsigned u[4]; bf16x8 v; } r;
  r.u[0] = a; r.u[1] = c; r.u[2] = b; r.u[3] = d;
  return r.v;
}

// ---------------- GEMM: C = A @ B^T, 128x64 tile, 32x32 MFMA ----------------
// grid (32,16) = 512 blocks -> 2 blocks/CU. 4 waves 2x2; wave = 64 rows x 32 cols.
// MODE 0: vt[bh*64+d][2048] bf16 (value projection, per-head transpose)
// MODE 1: fp32 row-major [M][1024]
template<int MODE>
__global__ __launch_bounds__(256) void gemm12864(const unsigned short* __restrict__ A,
                                                 const unsigned short* __restrict__ B,
                                                 void* __restrict__ C, int K) {
  __shared__ __attribute__((aligned(16))) char As[2][16384];   // 128 rows
  __shared__ __attribute__((aligned(16))) char Bs[2][8192];    // 64 rows
  int tid = threadIdx.x, w = tid >> 6, lane = tid & 63;
  int l31 = lane & 31, hi = lane >> 5;
  int wr = w >> 1, wc = w & 1;
  int bm = blockIdx.x, bn = blockIdx.y;
  const char* Ab = (const char*)A + (size_t)bm * 128 * (K * 2);
  const char* Bb = (const char*)B + (size_t)bn * 64 * (K * 2);
  size_t ld = (size_t)K * 2;

  f32x16 acc0 = {}, acc1 = {};
  stage64(Ab, ld, As[0], w, lane);
  stage64(Ab + 64 * ld, ld, As[0] + 8192, w, lane);
  stage64(Bb, ld, Bs[0], w, lane);
  __syncthreads();

  int nst = K >> 6;
  for (int kk = 0; kk < nst; ++kk) {
    int cur = kk & 1;
    if (kk + 1 < nst) {
      const char* An = Ab + (size_t)(kk + 1) * 128;
      const char* Bn = Bb + (size_t)(kk + 1) * 128;
      stage64(An, ld, As[cur ^ 1], w, lane);
      stage64(An + 64 * ld, ld, As[cur ^ 1] + 8192, w, lane);
      stage64(Bn, ld, Bs[cur ^ 1], w, lane);
    }
    __builtin_amdgcn_s_setprio(1);
#pragma unroll
    for (int ks = 0; ks < 4; ++ks) {
      bf16x8 a0 = rdfrag32(As[cur], wr * 64 + l31, ks * 2 + hi);
      bf16x8 a1 = rdfrag32(As[cur], wr * 64 + 32 + l31, ks * 2 + hi);
      bf16x8 b0 = rdfrag32(Bs[cur], wc * 32 + l31, ks * 2 + hi);
      acc0 = __builtin_amdgcn_mfma_f32_32x32x16_bf16(a0, b0, acc0, 0, 0, 0);
      acc1 = __builtin_amdgcn_mfma_f32_32x32x16_bf16(a1, b0, acc1, 0, 0, 0);
    }
    __builtin_amdgcn_s_setprio(0);
    __syncthreads();
  }

  if (MODE == 0) {
    unsigned short* vt = (unsigned short*)C;
    int d = wc * 32 + l31;
#pragma unroll
    for (int i = 0; i < 2; ++i) {
      f32x16 a = i ? acc1 : acc0;
      int rowb = bm * 128 + wr * 64 + i * 32;
#pragma unroll
      for (int qd = 0; qd < 4; ++qd) {
        int m0 = rowb + qd * 8 + hi * 4;          // 4 consecutive m (r=qd*4+0..3)
        int bb = m0 >> 11, n = m0 & 2047;
        int r0 = qd * 4;
        uint2 u;
        u.x = (unsigned)f2bf(a[r0]) | ((unsigned)f2bf(a[r0 + 1]) << 16);
        u.y = (unsigned)f2bf(a[r0 + 2]) | ((unsigned)f2bf(a[r0 + 3]) << 16);
        *(uint2*)(vt + ((size_t)((bb * 16 + bn) * 64 + d)) * 2048 + n) = u;
      }
    }
  } else {
    float* Cf = (float*)C;
    int rb = bm * 128 + wr * 64, cb = bn * 64 + wc * 32;
#pragma unroll
    for (int r = 0; r < 16; ++r) {
      int row = (r & 3) + 8 * (r >> 2) + 4 * hi;
      Cf[(size_t)(rb + row) * 1024 + cb + l31]      = acc0[r];
      Cf[(size_t)(rb + 32 + row) * 1024 + cb + l31] = acc1[r];
    }
  }
}

// ---------------- fused dense attention (8-wave, m-parallel groups) ----------
// Block: 128 q rows, 8 waves. Group grp=w>>2: grp0 even m-tiles, grp1 odd.
// 4-slot LDS ring; stage 2 tiles ahead; one barrier per superstep (2 tiles).
// Bias loaded directly as S C-init (log2 domain, L2-resident 8KB table);
// L = per-lane scalar sum. launch_bounds(512,2): >=128 VGPRs -> no spill
// (r9's (512,4) capped at 64 VGPR and spilled ~70MB of scratch traffic).
__global__ __launch_bounds__(512, 2) void flash_kernel(const unsigned short* __restrict__ xb,
                                                       const unsigned short* __restrict__ w1b,
                                                       const float* __restrict__ b1,
                                                       const unsigned short* __restrict__ w2b,
                                                       const float* __restrict__ b2l,
                                                       const unsigned short* __restrict__ vt,
                                                       unsigned short* __restrict__ aout) {
  __shared__ __attribute__((aligned(16))) char lds[65536];
  int tid = threadIdx.x, w = tid >> 6, lane = tid & 63;
  int wq = w & 3, grp = w >> 2;
  int l31 = lane & 31, hi = lane >> 5;
  // XCD-chunked swizzle: 512 blocks, 8 XCDs
  int f = blockIdx.x;
  int swz = ((f & 7) << 6) | (f >> 3);
  int qt = swz & 15, bh = swz >> 4;
  int b = bh >> 4, h = bh & 15;

  // ---- prologue: Q = relu(xh @ W1^T + b1) * log2e, in-register ----
  const char* px = (const char*)(xb + ((size_t)(b * 2048 + qt * 128)) * 1024 + h * 64);
  stage8(px, 2048, lds, w, lane);                          // x rows 0..63
  stage8(px + (size_t)64 * 2048, 2048, lds + 8192, w, lane); // x rows 64..127
  stage8((const char*)w1b, 128, lds + 32768, w, lane);     // W1 rows e 0..63
  __syncthreads();

  f32x16 h0 = loadb16(b1 + hi * 4);
  f32x16 h1 = loadb16(b1 + 32 + hi * 4);
  {
    const char* xt = lds + (wq >> 1) * 8192;
    int xr = (wq & 1) * 32 + l31;
#pragma unroll
    for (int ks = 0; ks < 4; ++ks) {
      bf16x8 xf = rdfrag32(xt, xr, ks * 2 + hi);           // B: x^T (col=q)
      bf16x8 wf0 = rdfrag32(lds + 32768, l31, ks * 2 + hi);
      h0 = __builtin_amdgcn_mfma_f32_32x32x16_bf16(wf0, xf, h0, 0, 0, 0);
      bf16x8 wf1 = rdfrag32(lds + 32768, 32 + l31, ks * 2 + hi);
      h1 = __builtin_amdgcn_mfma_f32_32x32x16_bf16(wf1, xf, h1, 0, 0, 0);
    }
  }
#pragma unroll
  for (int i = 0; i < 16; ++i) {
    h0[i] = fmaxf(h0[i], 0.f) * LOG2E;
    h1[i] = fmaxf(h1[i], 0.f) * LOG2E;
  }
  bf16x8 qb[4];
  qb[0] = pk_swap(h0[0], h0[1], h0[2], h0[3], h0[4], h0[5], h0[6], h0[7]);
  qb[1] = pk_swap(h0[8], h0[9], h0[10], h0[11], h0[12], h0[13], h0[14], h0[15]);
  qb[2] = pk_swap(h1[0], h1[1], h1[2], h1[3], h1[4], h1[5], h1[6], h1[7]);
  qb[3] = pk_swap(h1[8], h1[9], h1[10], h1[11], h1[12], h1[13], h1[14], h1[15]);
  __syncthreads();                                  // all waves done with prologue LDS

  // ---- stage tiles 0..3 into the 4-slot ring ----
  const char* vtb = (const char*)vt + (size_t)bh * 64 * 4096;
#pragma unroll
  for (int t = 0; t < 4; ++t) {
    stage8((const char*)w2b + (size_t)t * 8192, 128, lds + t * 8192, w, lane);
    stage8(vtb + (size_t)t * 128, 4096, lds + 32768 + t * 8192, w, lane);
  }
  f32x16 oA = {}, oB = {};
  float lrs0 = 0.f, lrs1 = 0.f, lrs2 = 0.f, lrs3 = 0.f;
  __syncthreads();                                  // tiles 0..3 landed

  for (int s = 0; s < 16; ++s) {
    int mt = 2 * s + grp;
    const char* Kc = lds + (mt & 3) * 8192;
    const char* Vc = lds + 32768 + (mt & 3) * 8192;

    // S^T = K @ Q + bias (log2 domain); C-init loaded from L2-resident table
    f32x16 s0, s1;
#pragma unroll
    for (int qd = 0; qd < 4; ++qd) {
      f32x4 p0 = *(const f32x4*)(b2l + mt * 64 + qd * 8 + hi * 4);
      f32x4 p1 = *(const f32x4*)(b2l + mt * 64 + 32 + qd * 8 + hi * 4);
#pragma unroll
      for (int j = 0; j < 4; ++j) {
        s0[qd * 4 + j] = p0[j];
        s1[qd * 4 + j] = p1[j];
      }
    }
    __builtin_amdgcn_s_setprio(1);
#pragma unroll
    for (int kt = 0; kt < 4; ++kt) {
      bf16x8 kf0 = rdfrag32(Kc, l31, kt * 2 + hi);
      s0 = __builtin_amdgcn_mfma_f32_32x32x16_bf16(kf0, qb[kt], s0, 0, 0, 0);
      bf16x8 kf1 = rdfrag32(Kc, 32 + l31, kt * 2 + hi);
      s1 = __builtin_amdgcn_mfma_f32_32x32x16_bf16(kf1, qb[kt], s1, 0, 0, 0);
    }
    __builtin_amdgcn_s_setprio(0);
    // p = 2^s ; per-lane scalar row-sum (4-way split)
#pragma unroll
    for (int i = 0; i < 16; ++i) {
      float t0, t1;
      asm("v_exp_f32 %0, %1" : "=v"(t0) : "v"(s0[i]));
      asm("v_exp_f32 %0, %1" : "=v"(t1) : "v"(s1[i]));
      s0[i] = t0; s1[i] = t1;
      if ((i & 3) == 0) { lrs0 += t0; lrs0 += t1; }
      else if ((i & 3) == 1) { lrs1 += t0; lrs1 += t1; }
      else if ((i & 3) == 2) { lrs2 += t0; lrs2 += t1; }
      else { lrs3 += t0; lrs3 += t1; }
    }
    bf16x8 pa0 = pk_swap(s0[0], s0[1], s0[2], s0[3], s0[4], s0[5], s0[6], s0[7]);
    bf16x8 pa1 = pk_swap(s0[8], s0[9], s0[10], s0[11], s0[12], s0[13], s0[14], s0[15]);
    bf16x8 pa2 = pk_swap(s1[0], s1[1], s1[2], s1[3], s1[4], s1[5], s1[6], s1[7]);
    bf16x8 pa3 = pk_swap(s1[8], s1[9], s1[10], s1[11], s1[12], s1[13], s1[14], s1[15]);
    // O += P @ V
    __builtin_amdgcn_s_setprio(1);
    {
      bf16x8 vf;
      vf = rdfrag32(Vc, l31, 0 + hi);
      oA = __builtin_amdgcn_mfma_f32_32x32x16_bf16(pa0, vf, oA, 0, 0, 0);
      vf = rdfrag32(Vc, 32 + l31, 0 + hi);
      oB = __builtin_amdgcn_mfma_f32_32x32x16_bf16(pa0, vf, oB, 0, 0, 0);
      vf = rdfrag32(Vc, l31, 2 + hi);
      oA = __builtin_amdgcn_mfma_f32_32x32x16_bf16(pa1, vf, oA, 0, 0, 0);
      vf = rdfrag32(Vc, 32 + l31, 2 + hi);
      oB = __builtin_amdgcn_mfma_f32_32x32x16_bf16(pa1, vf, oB, 0, 0, 0);
      vf = rdfrag32(Vc, l31, 4 + hi);
      oA = __builtin_amdgcn_mfma_f32_32x32x16_bf16(pa2, vf, oA, 0, 0, 0);
      vf = rdfrag32(Vc, 32 + l31, 4 + hi);
      oB = __builtin_amdgcn_mfma_f32_32x32x16_bf16(pa2, vf, oB, 0, 0, 0);
      vf = rdfrag32(Vc, l31, 6 + hi);
      oA = __builtin_amdgcn_mfma_f32_32x32x16_bf16(pa3, vf, oA, 0, 0, 0);
      vf = rdfrag32(Vc, 32 + l31, 6 + hi);
      oB = __builtin_amdgcn_mfma_f32_32x32x16_bf16(pa3, vf, oB, 0, 0, 0);
    }
    __builtin_amdgcn_s_setprio(0);
    __syncthreads();                       // both tiles of this superstep consumed
    if (s < 14) {                          // stage tiles 2s+4, 2s+5 (slots just freed)
      int t0 = 2 * s + 4, t1 = 2 * s + 5;
      stage8((const char*)w2b + (size_t)t0 * 8192, 128, lds + (t0 & 3) * 8192, w, lane);
      stage8(vtb + (size_t)t0 * 128, 4096, lds + 32768 + (t0 & 3) * 8192, w, lane);
      stage8((const char*)w2b + (size_t)t1 * 8192, 128, lds + (t1 & 3) * 8192, w, lane);
      stage8(vtb + (size_t)t1 * 128, 4096, lds + 32768 + (t1 & 3) * 8192, w, lane);
    }
  }

  // ---- combine groups (exact fp32 add), then finalize ----
  float lpart = (lrs0 + lrs1) + (lrs2 + lrs3);     // partial: this grp, own m-half
  float* comb = (float*)lds;
  if (grp == 1) {
    float* cb = comb + (wq * 64 + lane) * 36;      // 36-float stride, 16B aligned
#pragma unroll
    for (int i = 0; i < 4; ++i) {
      *(float4*)(cb + i * 4)      = make_float4(oA[i*4], oA[i*4+1], oA[i*4+2], oA[i*4+3]);
      *(float4*)(cb + 16 + i * 4) = make_float4(oB[i*4], oB[i*4+1], oB[i*4+2], oB[i*4+3]);
    }
    cb[32] = lpart;
  }
  __syncthreads();
  if (grp == 0) {
    float* cb = comb + (wq * 64 + lane) * 36;
#pragma unroll
    for (int i = 0; i < 4; ++i) {
      float4 a = *(const float4*)(cb + i * 4);
      float4 bq = *(const float4*)(cb + 16 + i * 4);
      oA[i*4] += a.x; oA[i*4+1] += a.y; oA[i*4+2] += a.z; oA[i*4+3] += a.w;
      oB[i*4] += bq.x; oB[i*4+1] += bq.y; oB[i*4+2] += bq.z; oB[i*4+3] += bq.w;
    }
    float l = lpart + cb[32];
    l += __shfl_xor(l, 32);                        // combine m-halves -> full L[q=l31]
    float inv = 1.f / l;
    float iv[16];
#pragma unroll
    for (int r = 0; r < 16; ++r)
      iv[r] = __shfl(inv, (r & 3) + 8 * (r >> 2) + 4 * hi);
    int nb = qt * 128 + wq * 32;
#pragma unroll
    for (int r = 0; r < 16; ++r) {
      int ql = (r & 3) + 8 * (r >> 2) + 4 * hi;
      size_t off = ((size_t)(b * 2048 + nb + ql)) * 1024 + h * 64 + l31;
      aout[off]      = f2bf(oA[r] * iv[r]);
      aout[off + 32] = f2bf(oB[r] * iv[r]);
    }
  }
}

// ---------------- launch ----------------
extern "C" void kernel_launch(void* const* d_in, const int* in_sizes, int n_in,
                              void* d_out, int out_size, void* d_ws, size_t ws_size,
                              hipStream_t stream) {
  (void)in_sizes; (void)n_in; (void)out_size; (void)ws_size;
  const float* x  = (const float*)d_in[0];
  const float* W1 = (const float*)d_in[1];
  const float* b1 = (const float*)d_in[2];
  const float* W2 = (const float*)d_in[3];
  const float* b2 = (const float*)d_in[4];
  const float* Wv = (const float*)d_in[5];
  const float* Wo = (const float*)d_in[6];
  float* out = (float*)d_out;

  char* ws = (char*)d_ws;
  unsigned short* xb   = (unsigned short*)(ws);             // x bf16      8 MB
  unsigned short* wvb  = (unsigned short*)(ws +  8388608);  // Wv bf16     2 MB
  unsigned short* wob  = (unsigned short*)(ws + 10485760);  // Wo bf16     2 MB
  unsigned short* w2b  = (unsigned short*)(ws + 12582912);  // W2 bf16   256 KB
  unsigned short* w1b  = (unsigned short*)(ws + 12845056);  // W1 bf16     8 KB
  float*          b2l  = (float*)         (ws + 12853248);  // b2*log2e    8 KB
  unsigned short* vt   = (unsigned short*)(ws + 21233664);  // V^T bf16    8 MB
  unsigned short* aout = (unsigned short*)(ws + 29622272);  // out_h bf16  8 MB

  prep_all<<<2049, 256, 0, stream>>>(x, Wv, Wo, W2, W1, b2,
                                     xb, wvb, wob, w2b, w1b, b2l);

  // value = x @ Wv^T -> vt[bh][d][m]
  gemm12864<0><<<dim3(32, 16), 256, 0, stream>>>(xb, wvb, (void*)vt, 1024);
  // fused: Q = relu(xh@W1^T+b1); softmax(Q@W2^T + b2) @ V -> aout (merged heads)
  flash_kernel<<<512, 512, 0, stream>>>(xb, w1b, b1, w2b, b2l, vt, aout);
  // out = aout @ Wo^T (fp32)
  gemm12864<1><<<dim3(32, 16), 256, 0, stream>>>(aout, wob, (void*)out, 1024);
}

// Round 11
// 91.259 us; speedup vs baseline: 1.5128x; 1.0324x over previous
//
#include <hip/hip_runtime.h>
#include <hip/hip_bf16.h>
#include <math.h>
#include <stdint.h>

// MultiHeadDenseAttention: B=2, H=16, N=2048, D=64, F=1024, M=2048
//  value = x @ Wv^T -> vt[bh][d][m]  (128x64 GEMM, 2 blocks/CU)
//  hid   = relu(xh @ W1^T + b1)      (fused into flash prologue, MFMA 32x32)
//  attn  = softmax(hid @ W2^T + b2)  (flash, swapped-QK^T, exp2, no-max,
//                                     bias C-init from LDS-resident table)
//  out_h = attn @ vh                 (fused, P in-register, 8-wave m-parallel)
//  out   = merge(out_h) @ Wo^T       (128x64 GEMM, fp32 out)

typedef __attribute__((ext_vector_type(8))) short bf16x8;
typedef __attribute__((ext_vector_type(4))) float f32x4;
typedef __attribute__((ext_vector_type(16))) float f32x16;

#define LOG2E 1.4426950408889634f

__device__ __forceinline__ unsigned short f2bf(float f) {
  union { float f; unsigned u; } v; v.f = f;
  unsigned r = v.u + 0x7FFFu + ((v.u >> 16) & 1u);   // round-to-nearest-even
  return (unsigned short)(r >> 16);
}

// ------------- one-shot prep: x/Wv/Wo/W2/W1 -> bf16, b2 -> b2*log2e ---------
__global__ __launch_bounds__(256) void prep_all(const float* __restrict__ x,
                                                const float* __restrict__ Wv,
                                                const float* __restrict__ Wo,
                                                const float* __restrict__ W2,
                                                const float* __restrict__ W1,
                                                const float* __restrict__ b2,
                                                unsigned short* __restrict__ xb,
                                                unsigned short* __restrict__ wvb,
                                                unsigned short* __restrict__ wob,
                                                unsigned short* __restrict__ w2b,
                                                unsigned short* __restrict__ w1b,
                                                float* __restrict__ b2l) {
  int bid = blockIdx.x;
  if (bid == 2048) {                                 // b2 * log2e table
    int i = threadIdx.x;
#pragma unroll
    for (int t = 0; t < 8; ++t) {
      int k = i * 8 + t;
      b2l[k] = b2[k] * LOG2E;
    }
    return;
  }
  int stride = 2048 * 256;
  for (int q = bid * 256 + threadIdx.x; q < 1606656; q += stride) {
    const float* s; unsigned short* d; int o;
    if (q < 1048576)      { s = x;  d = xb;  o = q; }
    else {
      int q2 = q - 1048576;
      if (q2 < 262144)      { s = Wv; d = wvb; o = q2; }
      else if (q2 < 524288) { s = Wo; d = wob; o = q2 - 262144; }
      else if (q2 < 557056) { s = W2; d = w2b; o = q2 - 524288; }
      else                  { s = W1; d = w1b; o = q2 - 557056; }
    }
    float4 v = *(const float4*)(s + (size_t)o * 4);
    uint2 u;
    u.x = (unsigned)f2bf(v.x) | ((unsigned)f2bf(v.y) << 16);
    u.y = (unsigned)f2bf(v.z) | ((unsigned)f2bf(v.w) << 16);
    *(uint2*)(d + (size_t)o * 4) = u;
  }
}

// ---------------- shared staging/frag helpers ----------------
// 4-wave version: wave w stages rows w*16..w*16+15 (2 insts)
__device__ __forceinline__ void stage64(const char* g, size_t ldbytes, char* lds,
                                        int w, int lane) {
#pragma unroll
  for (int t = 0; t < 2; ++t) {
    int row  = w * 16 + t * 8 + (lane >> 3);
    int csrc = (lane & 7) ^ (lane >> 3);
    const char* src = g + (size_t)row * ldbytes + (csrc << 4);
    char* dst = lds + ((w * 2 + t) << 10);
    __builtin_amdgcn_global_load_lds((const __attribute__((address_space(1))) void*)src,
                                     (__attribute__((address_space(3))) void*)dst,
                                     16, 0, 0);
  }
}

// 8-wave version: wave w stages rows w*8..w*8+7 (1 inst)
__device__ __forceinline__ void stage8(const char* g, size_t ldbytes, char* lds_,
                                       int w, int lane) {
  int row  = w * 8 + (lane >> 3);                 // row & 7 == lane>>3
  int csrc = (lane & 7) ^ (lane >> 3);
  const char* src = g + (size_t)row * ldbytes + (csrc << 4);
  char* dst = lds_ + (w << 10);
  __builtin_amdgcn_global_load_lds((const __attribute__((address_space(1))) void*)src,
                                   (__attribute__((address_space(3))) void*)dst,
                                   16, 0, 0);
}

// 32x32x16 operand fragment: row index linear (128B rows), chunk = kslice*2 + hi
__device__ __forceinline__ bf16x8 rdfrag32(const char* lds, int row, int chunk) {
  int c = chunk ^ (row & 7);
  return *(const bf16x8*)(lds + row * 128 + (c << 4));
}

// Load 16 fp32 in the 32x32 C/D reg layout: reg r <- p[(r&3) + 8*(r>>2)]
__device__ __forceinline__ f32x16 loadb16(const float* p) {
  f32x16 r;
#pragma unroll
  for (int qd = 0; qd < 4; ++qd) {
    float4 v = *(const float4*)(p + qd * 8);
    r[qd * 4 + 0] = v.x; r[qd * 4 + 1] = v.y; r[qd * 4 + 2] = v.z; r[qd * 4 + 3] = v.w;
  }
  return r;
}

// Build a 32x32x16 A/B-frag (8 bf16) from 16 C/D-layout f32 regs via cvt_pk+permlane.
__device__ __forceinline__ bf16x8 pk_swap(float r0, float r1, float r2, float r3,
                                          float r4, float r5, float r6, float r7) {
  unsigned a, b, c, d;
  asm("v_cvt_pk_bf16_f32 %0, %1, %2" : "=v"(a) : "v"(r0), "v"(r1));
  asm("v_cvt_pk_bf16_f32 %0, %1, %2" : "=v"(b) : "v"(r4), "v"(r5));
  asm("v_cvt_pk_bf16_f32 %0, %1, %2" : "=v"(c) : "v"(r2), "v"(r3));
  asm("v_cvt_pk_bf16_f32 %0, %1, %2" : "=v"(d) : "v"(r6), "v"(r7));
  asm("v_permlane32_swap_b32 %0, %1" : "+v"(a), "+v"(b));
  asm("v_permlane32_swap_b32 %0, %1" : "+v"(c), "+v"(d));
  union { unsigned u[4]; bf16x8 v; } r;
  r.u[0] = a; r.u[1] = c; r.u[2] = b; r.u[3] = d;
  return r.v;
}

// ---------------- GEMM: C = A @ B^T, 128x64 tile, 32x32 MFMA ----------------
// grid (32,16) = 512 blocks -> 2 blocks/CU. 4 waves 2x2; wave = 64 rows x 32 cols.
// MODE 0: vt[bh*64+d][2048] bf16 (value projection, per-head transpose)
// MODE 1: fp32 row-major [M][1024]
template<int MODE>
__global__ __launch_bounds__(256) void gemm12864(const unsigned short* __restrict__ A,
                                                 const unsigned short* __restrict__ B,
                                                 void* __restrict__ C, int K) {
  __shared__ __attribute__((aligned(16))) char As[2][16384];   // 128 rows
  __shared__ __attribute__((aligned(16))) char Bs[2][8192];    // 64 rows
  int tid = threadIdx.x, w = tid >> 6, lane = tid & 63;
  int l31 = lane & 31, hi = lane >> 5;
  int wr = w >> 1, wc = w & 1;
  int bm = blockIdx.x, bn = blockIdx.y;
  const char* Ab = (const char*)A + (size_t)bm * 128 * (K * 2);
  const char* Bb = (const char*)B + (size_t)bn * 64 * (K * 2);
  size_t ld = (size_t)K * 2;

  f32x16 acc0 = {}, acc1 = {};
  stage64(Ab, ld, As[0], w, lane);
  stage64(Ab + 64 * ld, ld, As[0] + 8192, w, lane);
  stage64(Bb, ld, Bs[0], w, lane);
  __syncthreads();

  int nst = K >> 6;
  for (int kk = 0; kk < nst; ++kk) {
    int cur = kk & 1;
    if (kk + 1 < nst) {
      const char* An = Ab + (size_t)(kk + 1) * 128;
      const char* Bn = Bb + (size_t)(kk + 1) * 128;
      stage64(An, ld, As[cur ^ 1], w, lane);
      stage64(An + 64 * ld, ld, As[cur ^ 1] + 8192, w, lane);
      stage64(Bn, ld, Bs[cur ^ 1], w, lane);
    }
    __builtin_amdgcn_s_setprio(1);
#pragma unroll
    for (int ks = 0; ks < 4; ++ks) {
      bf16x8 a0 = rdfrag32(As[cur], wr * 64 + l31, ks * 2 + hi);
      bf16x8 a1 = rdfrag32(As[cur], wr * 64 + 32 + l31, ks * 2 + hi);
      bf16x8 b0 = rdfrag32(Bs[cur], wc * 32 + l31, ks * 2 + hi);
      acc0 = __builtin_amdgcn_mfma_f32_32x32x16_bf16(a0, b0, acc0, 0, 0, 0);
      acc1 = __builtin_amdgcn_mfma_f32_32x32x16_bf16(a1, b0, acc1, 0, 0, 0);
    }
    __builtin_amdgcn_s_setprio(0);
    __syncthreads();
  }

  if (MODE == 0) {
    unsigned short* vt = (unsigned short*)C;
    int d = wc * 32 + l31;
#pragma unroll
    for (int i = 0; i < 2; ++i) {
      f32x16 a = i ? acc1 : acc0;
      int rowb = bm * 128 + wr * 64 + i * 32;
#pragma unroll
      for (int qd = 0; qd < 4; ++qd) {
        int m0 = rowb + qd * 8 + hi * 4;          // 4 consecutive m (r=qd*4+0..3)
        int bb = m0 >> 11, n = m0 & 2047;
        int r0 = qd * 4;
        uint2 u;
        u.x = (unsigned)f2bf(a[r0]) | ((unsigned)f2bf(a[r0 + 1]) << 16);
        u.y = (unsigned)f2bf(a[r0 + 2]) | ((unsigned)f2bf(a[r0 + 3]) << 16);
        *(uint2*)(vt + ((size_t)((bb * 16 + bn) * 64 + d)) * 2048 + n) = u;
      }
    }
  } else {
    float* Cf = (float*)C;
    int rb = bm * 128 + wr * 64, cb = bn * 64 + wc * 32;
#pragma unroll
    for (int r = 0; r < 16; ++r) {
      int row = (r & 3) + 8 * (r >> 2) + 4 * hi;
      Cf[(size_t)(rb + row) * 1024 + cb + l31]      = acc0[r];
      Cf[(size_t)(rb + 32 + row) * 1024 + cb + l31] = acc1[r];
    }
  }
}

// ---------------- fused dense attention (8-wave, m-parallel groups) ----------
// Block: 128 q rows, 8 waves. Group grp=w>>2: grp0 even m-tiles, grp1 odd.
// 4-slot LDS ring; stage 2 tiles ahead; one barrier per superstep (2 tiles).
// Bias table (b2*log2e, 8KB fp32) LDS-resident: per-superstep C-init is 8
// broadcast ds_read_b128 (off the VMEM critical path). L = per-lane scalar sum.
__global__ __launch_bounds__(512, 2) void flash_kernel(const unsigned short* __restrict__ xb,
                                                       const unsigned short* __restrict__ w1b,
                                                       const float* __restrict__ b1,
                                                       const unsigned short* __restrict__ w2b,
                                                       const float* __restrict__ b2l,
                                                       const unsigned short* __restrict__ vt,
                                                       unsigned short* __restrict__ aout) {
  __shared__ __attribute__((aligned(16))) char lds[73728];   // 64KB ring + 8KB bias
  int tid = threadIdx.x, w = tid >> 6, lane = tid & 63;
  int wq = w & 3, grp = w >> 2;
  int l31 = lane & 31, hi = lane >> 5;
  // XCD-chunked swizzle: 512 blocks, 8 XCDs
  int f = blockIdx.x;
  int swz = ((f & 7) << 6) | (f >> 3);
  int qt = swz & 15, bh = swz >> 4;
  int b = bh >> 4, h = bh & 15;

  // ---- prologue: stage x, W1, and the bias table; Q = relu(xh@W1^T+b1)*log2e ----
  const char* px = (const char*)(xb + ((size_t)(b * 2048 + qt * 128)) * 1024 + h * 64);
  stage8(px, 2048, lds, w, lane);                          // x rows 0..63
  stage8(px + (size_t)64 * 2048, 2048, lds + 8192, w, lane); // x rows 64..127
  stage8((const char*)w1b, 128, lds + 32768, w, lane);     // W1 rows e 0..63
  {                                                        // b2l -> LDS (linear 8KB)
    const char* src = (const char*)b2l + (w << 10) + (lane << 4);
    char* dst = lds + 65536 + (w << 10);
    __builtin_amdgcn_global_load_lds((const __attribute__((address_space(1))) void*)src,
                                     (__attribute__((address_space(3))) void*)dst,
                                     16, 0, 0);
  }
  __syncthreads();

  f32x16 h0 = loadb16(b1 + hi * 4);
  f32x16 h1 = loadb16(b1 + 32 + hi * 4);
  {
    const char* xt = lds + (wq >> 1) * 8192;
    int xr = (wq & 1) * 32 + l31;
#pragma unroll
    for (int ks = 0; ks < 4; ++ks) {
      bf16x8 xf = rdfrag32(xt, xr, ks * 2 + hi);           // B: x^T (col=q)
      bf16x8 wf0 = rdfrag32(lds + 32768, l31, ks * 2 + hi);
      h0 = __builtin_amdgcn_mfma_f32_32x32x16_bf16(wf0, xf, h0, 0, 0, 0);
      bf16x8 wf1 = rdfrag32(lds + 32768, 32 + l31, ks * 2 + hi);
      h1 = __builtin_amdgcn_mfma_f32_32x32x16_bf16(wf1, xf, h1, 0, 0, 0);
    }
  }
#pragma unroll
  for (int i = 0; i < 16; ++i) {
    h0[i] = fmaxf(h0[i], 0.f) * LOG2E;
    h1[i] = fmaxf(h1[i], 0.f) * LOG2E;
  }
  bf16x8 qb[4];
  qb[0] = pk_swap(h0[0], h0[1], h0[2], h0[3], h0[4], h0[5], h0[6], h0[7]);
  qb[1] = pk_swap(h0[8], h0[9], h0[10], h0[11], h0[12], h0[13], h0[14], h0[15]);
  qb[2] = pk_swap(h1[0], h1[1], h1[2], h1[3], h1[4], h1[5], h1[6], h1[7]);
  qb[3] = pk_swap(h1[8], h1[9], h1[10], h1[11], h1[12], h1[13], h1[14], h1[15]);
  __syncthreads();                                  // all waves done with prologue LDS

  // ---- stage tiles 0..3 into the 4-slot ring ----
  const char* vtb = (const char*)vt + (size_t)bh * 64 * 4096;
#pragma unroll
  for (int t = 0; t < 4; ++t) {
    stage8((const char*)w2b + (size_t)t * 8192, 128, lds + t * 8192, w, lane);
    stage8(vtb + (size_t)t * 128, 4096, lds + 32768 + t * 8192, w, lane);
  }
  f32x16 oA = {}, oB = {};
  float lrs0 = 0.f, lrs1 = 0.f, lrs2 = 0.f, lrs3 = 0.f;
  const float* bl = (const float*)(lds + 65536);    // LDS bias table
  __syncthreads();                                  // tiles 0..3 landed

  for (int s = 0; s < 16; ++s) {
    int mt = 2 * s + grp;
    const char* Kc = lds + (mt & 3) * 8192;
    const char* Vc = lds + 32768 + (mt & 3) * 8192;

    // S^T = K @ Q + bias (log2 domain); C-init via broadcast LDS reads
    f32x16 s0, s1;
#pragma unroll
    for (int qd = 0; qd < 4; ++qd) {
      f32x4 p0 = *(const f32x4*)(bl + mt * 64 + qd * 8 + hi * 4);
      f32x4 p1 = *(const f32x4*)(bl + mt * 64 + 32 + qd * 8 + hi * 4);
#pragma unroll
      for (int j = 0; j < 4; ++j) {
        s0[qd * 4 + j] = p0[j];
        s1[qd * 4 + j] = p1[j];
      }
    }
    __builtin_amdgcn_s_setprio(1);
#pragma unroll
    for (int kt = 0; kt < 4; ++kt) {
      bf16x8 kf0 = rdfrag32(Kc, l31, kt * 2 + hi);
      s0 = __builtin_amdgcn_mfma_f32_32x32x16_bf16(kf0, qb[kt], s0, 0, 0, 0);
      bf16x8 kf1 = rdfrag32(Kc, 32 + l31, kt * 2 + hi);
      s1 = __builtin_amdgcn_mfma_f32_32x32x16_bf16(kf1, qb[kt], s1, 0, 0, 0);
    }
    __builtin_amdgcn_s_setprio(0);
    // p = 2^s ; per-lane scalar row-sum (4-way split)
#pragma unroll
    for (int i = 0; i < 16; ++i) {
      float t0, t1;
      asm("v_exp_f32 %0, %1" : "=v"(t0) : "v"(s0[i]));
      asm("v_exp_f32 %0, %1" : "=v"(t1) : "v"(s1[i]));
      s0[i] = t0; s1[i] = t1;
      if ((i & 3) == 0) { lrs0 += t0; lrs0 += t1; }
      else if ((i & 3) == 1) { lrs1 += t0; lrs1 += t1; }
      else if ((i & 3) == 2) { lrs2 += t0; lrs2 += t1; }
      else { lrs3 += t0; lrs3 += t1; }
    }
    bf16x8 pa0 = pk_swap(s0[0], s0[1], s0[2], s0[3], s0[4], s0[5], s0[6], s0[7]);
    bf16x8 pa1 = pk_swap(s0[8], s0[9], s0[10], s0[11], s0[12], s0[13], s0[14], s0[15]);
    bf16x8 pa2 = pk_swap(s1[0], s1[1], s1[2], s1[3], s1[4], s1[5], s1[6], s1[7]);
    bf16x8 pa3 = pk_swap(s1[8], s1[9], s1[10], s1[11], s1[12], s1[13], s1[14], s1[15]);
    // O += P @ V
    __builtin_amdgcn_s_setprio(1);
    {
      bf16x8 vf;
      vf = rdfrag32(Vc, l31, 0 + hi);
      oA = __builtin_amdgcn_mfma_f32_32x32x16_bf16(pa0, vf, oA, 0, 0, 0);
      vf = rdfrag32(Vc, 32 + l31, 0 + hi);
      oB = __builtin_amdgcn_mfma_f32_32x32x16_bf16(pa0, vf, oB, 0, 0, 0);
      vf = rdfrag32(Vc, l31, 2 + hi);
      oA = __builtin_amdgcn_mfma_f32_32x32x16_bf16(pa1, vf, oA, 0, 0, 0);
      vf = rdfrag32(Vc, 32 + l31, 2 + hi);
      oB = __builtin_amdgcn_mfma_f32_32x32x16_bf16(pa1, vf, oB, 0, 0, 0);
      vf = rdfrag32(Vc, l31, 4 + hi);
      oA = __builtin_amdgcn_mfma_f32_32x32x16_bf16(pa2, vf, oA, 0, 0, 0);
      vf = rdfrag32(Vc, 32 + l31, 4 + hi);
      oB = __builtin_amdgcn_mfma_f32_32x32x16_bf16(pa2, vf, oB, 0, 0, 0);
      vf = rdfrag32(Vc, l31, 6 + hi);
      oA = __builtin_amdgcn_mfma_f32_32x32x16_bf16(pa3, vf, oA, 0, 0, 0);
      vf = rdfrag32(Vc, 32 + l31, 6 + hi);
      oB = __builtin_amdgcn_mfma_f32_32x32x16_bf16(pa3, vf, oB, 0, 0, 0);
    }
    __builtin_amdgcn_s_setprio(0);
    __syncthreads();                       // both tiles of this superstep consumed
    if (s < 14) {                          // stage tiles 2s+4, 2s+5 (slots just freed)
      int t0 = 2 * s + 4, t1 = 2 * s + 5;
      stage8((const char*)w2b + (size_t)t0 * 8192, 128, lds + (t0 & 3) * 8192, w, lane);
      stage8(vtb + (size_t)t0 * 128, 4096, lds + 32768 + (t0 & 3) * 8192, w, lane);
      stage8((const char*)w2b + (size_t)t1 * 8192, 128, lds + (t1 & 3) * 8192, w, lane);
      stage8(vtb + (size_t)t1 * 128, 4096, lds + 32768 + (t1 & 3) * 8192, w, lane);
    }
  }

  // ---- combine groups (exact fp32 add), then finalize ----
  float lpart = (lrs0 + lrs1) + (lrs2 + lrs3);     // partial: this grp, own m-half
  float* comb = (float*)lds;
  if (grp == 1) {
    float* cb = comb + (wq * 64 + lane) * 36;      // 36-float stride, 16B aligned
#pragma unroll
    for (int i = 0; i < 4; ++i) {
      *(float4*)(cb + i * 4)      = make_float4(oA[i*4], oA[i*4+1], oA[i*4+2], oA[i*4+3]);
      *(float4*)(cb + 16 + i * 4) = make_float4(oB[i*4], oB[i*4+1], oB[i*4+2], oB[i*4+3]);
    }
    cb[32] = lpart;
  }
  __syncthreads();
  if (grp == 0) {
    float* cb = comb + (wq * 64 + lane) * 36;
#pragma unroll
    for (int i = 0; i < 4; ++i) {
      float4 a = *(const float4*)(cb + i * 4);
      float4 bq = *(const float4*)(cb + 16 + i * 4);
      oA[i*4] += a.x; oA[i*4+1] += a.y; oA[i*4+2] += a.z; oA[i*4+3] += a.w;
      oB[i*4] += bq.x; oB[i*4+1] += bq.y; oB[i*4+2] += bq.z; oB[i*4+3] += bq.w;
    }
    float l = lpart + cb[32];
    l += __shfl_xor(l, 32);                        // combine m-halves -> full L[q=l31]
    float inv = 1.f / l;
    float iv[16];
#pragma unroll
    for (int r = 0; r < 16; ++r)
      iv[r] = __shfl(inv, (r & 3) + 8 * (r >> 2) + 4 * hi);
    int nb = qt * 128 + wq * 32;
#pragma unroll
    for (int r = 0; r < 16; ++r) {
      int ql = (r & 3) + 8 * (r >> 2) + 4 * hi;
      size_t off = ((size_t)(b * 2048 + nb + ql)) * 1024 + h * 64 + l31;
      aout[off]      = f2bf(oA[r] * iv[r]);
      aout[off + 32] = f2bf(oB[r] * iv[r]);
    }
  }
}

// ---------------- launch ----------------
extern "C" void kernel_launch(void* const* d_in, const int* in_sizes, int n_in,
                              void* d_out, int out_size, void* d_ws, size_t ws_size,
                              hipStream_t stream) {
  (void)in_sizes; (void)n_in; (void)out_size; (void)ws_size;
  const float* x  = (const float*)d_in[0];
  const float* W1 = (const float*)d_in[1];
  const float* b1 = (const float*)d_in[2];
  const float* W2 = (const float*)d_in[3];
  const float* b2 = (const float*)d_in[4];
  const float* Wv = (const float*)d_in[5];
  const float* Wo = (const float*)d_in[6];
  float* out = (float*)d_out;

  char* ws = (char*)d_ws;
  unsigned short* xb   = (unsigned short*)(ws);             // x bf16      8 MB
  unsigned short* wvb  = (unsigned short*)(ws +  8388608);  // Wv bf16     2 MB
  unsigned short* wob  = (unsigned short*)(ws + 10485760);  // Wo bf16     2 MB
  unsigned short* w2b  = (unsigned short*)(ws + 12582912);  // W2 bf16   256 KB
  unsigned short* w1b  = (unsigned short*)(ws + 12845056);  // W1 bf16     8 KB
  float*          b2l  = (float*)         (ws + 12853248);  // b2*log2e    8 KB
  unsigned short* vt   = (unsigned short*)(ws + 21233664);  // V^T bf16    8 MB
  unsigned short* aout = (unsigned short*)(ws + 29622272);  // out_h bf16  8 MB

  prep_all<<<2049, 256, 0, stream>>>(x, Wv, Wo, W2, W1, b2,
                                     xb, wvb, wob, w2b, w1b, b2l);

  // value = x @ Wv^T -> vt[bh][d][m]
  gemm12864<0><<<dim3(32, 16), 256, 0, stream>>>(xb, wvb, (void*)vt, 1024);
  // fused: Q = relu(xh@W1^T+b1); softmax(Q@W2^T + b2) @ V -> aout (merged heads)
  flash_kernel<<<512, 512, 0, stream>>>(xb, w1b, b1, w2b, b2l, vt, aout);
  // out = aout @ Wo^T (fp32)
  gemm12864<1><<<dim3(32, 16), 256, 0, stream>>>(aout, wob, (void*)out, 1024);
}